// Round 14
// baseline (106.062 us; speedup 1.0000x reference)
//
#include <hip/hip_runtime.h>

// GAT: N=4096, F_IN=128, F_HID=64, H=4, F_OUT=64, alpha=0.2
// R14 = ATTRIBUTION ROUND: pipeline launched twice (idempotent) to split
// kernel-time vs dispatch-overhead. Kernels identical to R12 (56.26 baseline).
#define GN 4096
#define F_IN 128
#define F_HID 64
#define NHEADS 4
#define F_OUT 64
#define ALPHA 0.2f
#define NGEMM 512          // GEMM blocks in K1 (8 nodes each), placed FIRST

// workspace layout (bytes)
#define OFF_WH     0           // GN*256*4 = 4 MB   [i][head*64+f]
#define OFF_SRC1   4194304     // GN*4*4             [i][head]
#define OFF_DST1   4259840     // GN*4*4
#define OFF_WH2    4325376     // GN*64*4 = 1 MB
#define OFF_SRC2   5373952     // GN*4
#define OFF_DST2   5390336     // GN*4
#define OFF_BM     5406720     // GN*256 ushort = 2 MB

// ===== K1: [GEMM blocks 0..511] + [bitmask scan blocks 512..4607, 1 row each] =====
__global__ __launch_bounds__(256) void prep_kernel(
        const float* __restrict__ adj, const float* __restrict__ x,
        const float* __restrict__ linW, const float* __restrict__ linb,
        const float* __restrict__ Wheads, const float* __restrict__ aheads,
        float* __restrict__ Wh, float* __restrict__ src1, float* __restrict__ dst1,
        unsigned short* __restrict__ bm) {
    __shared__ struct { float xs[8][128]; float hs[8][128]; } sm;
    const int tid = threadIdx.x;

    if (blockIdx.x >= NGEMM) {
        const int row = blockIdx.x - NGEMM;
        const float4* a4 = (const float4*)(adj + (size_t)row * GN) + tid * 4;
        float4 v0 = a4[0], v1 = a4[1], v2 = a4[2], v3 = a4[3];
        unsigned msk = 0;
        msk |= (v0.x > 0.0f) ? 1u : 0u;         msk |= (v0.y > 0.0f) ? 2u : 0u;
        msk |= (v0.z > 0.0f) ? 4u : 0u;         msk |= (v0.w > 0.0f) ? 8u : 0u;
        msk |= (v1.x > 0.0f) ? 16u : 0u;        msk |= (v1.y > 0.0f) ? 32u : 0u;
        msk |= (v1.z > 0.0f) ? 64u : 0u;        msk |= (v1.w > 0.0f) ? 128u : 0u;
        msk |= (v2.x > 0.0f) ? 256u : 0u;       msk |= (v2.y > 0.0f) ? 512u : 0u;
        msk |= (v2.z > 0.0f) ? 1024u : 0u;      msk |= (v2.w > 0.0f) ? 2048u : 0u;
        msk |= (v3.x > 0.0f) ? 4096u : 0u;      msk |= (v3.y > 0.0f) ? 8192u : 0u;
        msk |= (v3.z > 0.0f) ? 16384u : 0u;     msk |= (v3.w > 0.0f) ? 32768u : 0u;
        bm[row * 256 + tid] = (unsigned short)msk;
        return;
    }

    // ---- fused GEMMs: h = x@linW+b ; Wh = h@W_heads ; src1/dst1 (8 nodes) ----
    const int i0 = blockIdx.x * 8;
    #pragma unroll
    for (int t = 0; t < 4; ++t) {
        int e = t * 256 + tid;
        sm.xs[e >> 7][e & 127] = x[(size_t)i0 * 128 + e];
    }
    __syncthreads();
    {
        const int k = tid & 127;
        const int n0 = tid >> 7;
        float bk = linb[k];
        float a0 = bk, a1 = bk, a2 = bk, a3 = bk;
        for (int j = 0; j < 128; ++j) {
            float w = linW[j * 128 + k];
            a0 += sm.xs[n0][j] * w;
            a1 += sm.xs[n0 + 2][j] * w;
            a2 += sm.xs[n0 + 4][j] * w;
            a3 += sm.xs[n0 + 6][j] * w;
        }
        sm.hs[n0][k] = a0; sm.hs[n0 + 2][k] = a1;
        sm.hs[n0 + 4][k] = a2; sm.hs[n0 + 6][k] = a3;
    }
    __syncthreads();
    {
        const int hd = tid >> 6, f = tid & 63;
        float acc[8] = {0, 0, 0, 0, 0, 0, 0, 0};
        const float* Wp = Wheads + (size_t)hd * F_IN * F_HID + f;
        for (int j = 0; j < 128; ++j) {
            float w = Wp[j * 64];
            #pragma unroll
            for (int n = 0; n < 8; ++n) acc[n] += sm.hs[n][j] * w;
        }
        const float as = aheads[hd * 128 + f];
        const float ad = aheads[hd * 128 + 64 + f];
        #pragma unroll
        for (int n = 0; n < 8; ++n) {
            Wh[(size_t)(i0 + n) * 256 + hd * 64 + f] = acc[n];
            float sv = acc[n] * as, dv = acc[n] * ad;
            #pragma unroll
            for (int o = 32; o > 0; o >>= 1) {
                sv += __shfl_xor(sv, o, 64);
                dv += __shfl_xor(dv, o, 64);
            }
            if (f == 0) { src1[(i0 + n) * 4 + hd] = sv; dst1[(i0 + n) * 4 + hd] = dv; }
        }
    }
}

// --- per-wave: build this row's neighbor list from the bitmask into LDS sidx ---
__device__ __forceinline__ int build_row_nbrs(const unsigned short* __restrict__ bm,
                                              int row, int lane, int* sidx) {
    unsigned long long bits =
        ((const unsigned long long*)(bm + (size_t)row * 256))[lane];
    int c = __popcll(bits);
    int inc = c;
    #pragma unroll
    for (int o = 1; o < 64; o <<= 1) {
        int n = __shfl_up(inc, o, 64);
        if (lane >= o) inc += n;
    }
    int p = inc - c;
    const int deg = __shfl(inc, 63, 64);
    const int col0 = lane * 64;
    while (bits) {
        int k = __ffsll((long long)bits) - 1;
        if (p < 136) sidx[p] = col0 + k;
        ++p;
        bits &= bits - 1;
    }
    const int deg4 = (deg + 3) & ~3;
    if (lane < deg4 - deg) sidx[deg + lane] = 0;   // pads: weight will be exactly 0
    return deg;
}

// ===== K2: layer-1 attention (all heads, wave/row) + Wend projection, hcat in LDS =====
__global__ __launch_bounds__(256) void attn_mid_kernel(
        const float* __restrict__ Wh, const float* __restrict__ src1,
        const float* __restrict__ dst1, const float* __restrict__ Wend,
        const float* __restrict__ aend, float* __restrict__ Wh2,
        float* __restrict__ src2, float* __restrict__ dst2,
        const unsigned short* __restrict__ bm) {
    __shared__ float ps[4][528];
    __shared__ float hcat[4][256];
    __shared__ int   sidx[4][136];
    const int wave = threadIdx.x >> 6;
    const int lane = threadIdx.x & 63;
    const int row  = blockIdx.x * 4 + wave;

    const int deg = build_row_nbrs(bm, row, lane, sidx[wave]);
    const int* nb = sidx[wave];
    const int nchunk = (deg + 63) >> 6;

    const float4 s4 = ((const float4*)src1)[row];
    float4 ev[2];
    float4 m4 = make_float4(-1e30f, -1e30f, -1e30f, -1e30f);
    for (int c = 0; c < nchunk; ++c) {
        int t = c * 64 + lane;
        float4 e = make_float4(-1e30f, -1e30f, -1e30f, -1e30f);
        if (t < deg) {
            int j = nb[t];
            float4 d = ((const float4*)dst1)[j];
            e.x = s4.x + d.x; e.x = (e.x > 0.0f) ? e.x : ALPHA * e.x;
            e.y = s4.y + d.y; e.y = (e.y > 0.0f) ? e.y : ALPHA * e.y;
            e.z = s4.z + d.z; e.z = (e.z > 0.0f) ? e.z : ALPHA * e.z;
            e.w = s4.w + d.w; e.w = (e.w > 0.0f) ? e.w : ALPHA * e.w;
        }
        ev[c] = e;
        m4.x = fmaxf(m4.x, e.x); m4.y = fmaxf(m4.y, e.y);
        m4.z = fmaxf(m4.z, e.z); m4.w = fmaxf(m4.w, e.w);
    }
    #pragma unroll
    for (int o = 32; o > 0; o >>= 1) {
        m4.x = fmaxf(m4.x, __shfl_xor(m4.x, o, 64));
        m4.y = fmaxf(m4.y, __shfl_xor(m4.y, o, 64));
        m4.z = fmaxf(m4.z, __shfl_xor(m4.z, o, 64));
        m4.w = fmaxf(m4.w, __shfl_xor(m4.w, o, 64));
    }
    float4 l4 = make_float4(0.f, 0.f, 0.f, 0.f);
    for (int c = 0; c < nchunk; ++c) {
        ev[c].x = expf(ev[c].x - m4.x); l4.x += ev[c].x;
        ev[c].y = expf(ev[c].y - m4.y); l4.y += ev[c].y;
        ev[c].z = expf(ev[c].z - m4.z); l4.z += ev[c].z;
        ev[c].w = expf(ev[c].w - m4.w); l4.w += ev[c].w;
    }
    #pragma unroll
    for (int o = 32; o > 0; o >>= 1) {
        l4.x += __shfl_xor(l4.x, o, 64);
        l4.y += __shfl_xor(l4.y, o, 64);
        l4.z += __shfl_xor(l4.z, o, 64);
        l4.w += __shfl_xor(l4.w, o, 64);
    }
    const float4 inv = make_float4(1.f / l4.x, 1.f / l4.y, 1.f / l4.z, 1.f / l4.w);
    for (int c = 0; c < nchunk; ++c) {
        int t = c * 64 + lane;
        float4 p = make_float4(ev[c].x * inv.x, ev[c].y * inv.y,
                               ev[c].z * inv.z, ev[c].w * inv.w);
        ((float4*)&ps[wave][0])[t] = p;
    }

    const int hl = lane >> 4;
    const float4* Wh4 = (const float4*)Wh;
    float4 acc = make_float4(0.f, 0.f, 0.f, 0.f);
    const int deg4 = (deg + 3) & ~3;
    for (int t = 0; t < deg4; t += 4) {
        int4 jj = *(const int4*)(nb + t);
        float4 w0 = Wh4[(size_t)jj.x * 64 + lane];
        float4 w1 = Wh4[(size_t)jj.y * 64 + lane];
        float4 w2 = Wh4[(size_t)jj.z * 64 + lane];
        float4 w3 = Wh4[(size_t)jj.w * 64 + lane];
        const float* pp = &ps[wave][t * 4 + hl];
        float p0 = pp[0], p1 = pp[4], p2 = pp[8], p3 = pp[12];
        acc.x += p0 * w0.x + p1 * w1.x + p2 * w2.x + p3 * w3.x;
        acc.y += p0 * w0.y + p1 * w1.y + p2 * w2.y + p3 * w3.y;
        acc.z += p0 * w0.z + p1 * w1.z + p2 * w2.z + p3 * w3.z;
        acc.w += p0 * w0.w + p1 * w1.w + p2 * w2.w + p3 * w3.w;
    }
    acc.x = (acc.x > 0.0f) ? acc.x : expm1f(acc.x);
    acc.y = (acc.y > 0.0f) ? acc.y : expm1f(acc.y);
    acc.z = (acc.z > 0.0f) ? acc.z : expm1f(acc.z);
    acc.w = (acc.w > 0.0f) ? acc.w : expm1f(acc.w);
    ((float4*)hcat[wave])[lane] = acc;

    float a0 = 0.f, a1 = 0.f, a2 = 0.f, a3 = 0.f;
    const float* Wp = Wend + lane;
    #pragma unroll 4
    for (int j = 0; j < 256; j += 4) {
        a0 += hcat[wave][j    ] * Wp[(j    ) * 64];
        a1 += hcat[wave][j + 1] * Wp[(j + 1) * 64];
        a2 += hcat[wave][j + 2] * Wp[(j + 2) * 64];
        a3 += hcat[wave][j + 3] * Wp[(j + 3) * 64];
    }
    float aa = (a0 + a1) + (a2 + a3);
    Wh2[(size_t)row * 64 + lane] = aa;
    float s0 = aa * aend[lane], d0 = aa * aend[64 + lane];
    #pragma unroll
    for (int o = 32; o > 0; o >>= 1) {
        s0 += __shfl_xor(s0, o, 64); d0 += __shfl_xor(d0, o, 64);
    }
    if (lane == 0) { src2[row] = s0; dst2[row] = d0; }
}

// ===== K3: layer-2 attention + elu + final row softmax; wave per row =====
__global__ __launch_bounds__(256) void attn2_kernel(
        const float* __restrict__ Wh2, const float* __restrict__ src,
        const float* __restrict__ dst, const unsigned short* __restrict__ bm,
        float* __restrict__ out) {
    __shared__ int sidx[4][136];
    const int wave = threadIdx.x >> 6;
    const int lane = threadIdx.x & 63;
    const int row  = blockIdx.x * 4 + wave;

    const int deg = build_row_nbrs(bm, row, lane, sidx[wave]);
    const int* nb = sidx[wave];
    const float s_i = src[row];

    float e[2];
    #pragma unroll
    for (int c = 0; c < 2; ++c) {
        int t = c * 64 + lane;
        float ev = -1e30f;
        if (t < deg) {
            int j = nb[t];
            ev = s_i + dst[j];
            ev = (ev > 0.0f) ? ev : ALPHA * ev;
        }
        e[c] = ev;
    }
    float m = fmaxf(e[0], e[1]);
    #pragma unroll
    for (int o = 32; o > 0; o >>= 1) m = fmaxf(m, __shfl_xor(m, o, 64));
    float l = 0.0f;
    #pragma unroll
    for (int c = 0; c < 2; ++c) { e[c] = expf(e[c] - m); l += e[c]; }
    #pragma unroll
    for (int o = 32; o > 0; o >>= 1) l += __shfl_xor(l, o, 64);

    float accA = 0.0f, accB = 0.0f;
    const float* W2 = Wh2 + lane;
    #pragma unroll
    for (int c = 0; c < 2; ++c) {
        int base = c * 64;
        if (base >= deg) break;
        int nmax = deg - base; if (nmax > 64) nmax = 64;
        int n4 = (nmax + 3) & ~3;
        for (int t = 0; t < n4; t += 4) {
            int4 jj = *(const int4*)(nb + base + t);
            float w0 = W2[(size_t)jj.x * 64];
            float w1 = W2[(size_t)jj.y * 64];
            float w2 = W2[(size_t)jj.z * 64];
            float w3 = W2[(size_t)jj.w * 64];
            float p0 = __shfl(e[c], t, 64),     p1 = __shfl(e[c], t + 1, 64);
            float p2 = __shfl(e[c], t + 2, 64), p3 = __shfl(e[c], t + 3, 64);
            accA += p0 * w0 + p2 * w2;
            accB += p1 * w1 + p3 * w3;
        }
    }
    float v = (accA + accB) / l;
    v = (v > 0.0f) ? v : expm1f(v);    // elu

    float mm = v;
    #pragma unroll
    for (int o = 32; o > 0; o >>= 1) mm = fmaxf(mm, __shfl_xor(mm, o, 64));
    float ee = expf(v - mm);
    float ss = ee;
    #pragma unroll
    for (int o = 32; o > 0; o >>= 1) ss += __shfl_xor(ss, o, 64);
    out[(size_t)row * F_OUT + lane] = ee / ss;
}

extern "C" void kernel_launch(void* const* d_in, const int* in_sizes, int n_in,
                              void* d_out, int out_size, void* d_ws, size_t ws_size,
                              hipStream_t stream) {
    const float* x      = (const float*)d_in[0];
    const float* adj    = (const float*)d_in[1];
    const float* lin_W  = (const float*)d_in[2];
    const float* lin_b  = (const float*)d_in[3];
    const float* Wheads = (const float*)d_in[4];
    const float* aheads = (const float*)d_in[5];
    const float* Wend   = (const float*)d_in[6];
    const float* aend   = (const float*)d_in[7];
    float* out = (float*)d_out;

    char* ws = (char*)d_ws;
    float* Wh   = (float*)(ws + OFF_WH);
    float* src1 = (float*)(ws + OFF_SRC1);
    float* dst1 = (float*)(ws + OFF_DST1);
    float* Wh2  = (float*)(ws + OFF_WH2);
    float* src2 = (float*)(ws + OFF_SRC2);
    float* dst2 = (float*)(ws + OFF_DST2);
    unsigned short* bm = (unsigned short*)(ws + OFF_BM);

    // ATTRIBUTION: run the (idempotent, deterministic) pipeline TWICE.
    // dur_us - 56.26 ≈ t_prep + t_mid + t_attn2 + 3*gap  -> splits kernel time
    // from fixed dispatch/ramp overhead. Output is identical either way.
    for (int rep = 0; rep < 2; ++rep) {
        prep_kernel<<<NGEMM + GN, 256, 0, stream>>>(adj, x, lin_W, lin_b, Wheads,
                                                    aheads, Wh, src1, dst1, bm);
        attn_mid_kernel<<<GN / 4, 256, 0, stream>>>(Wh, src1, dst1, Wend, aend,
                                                    Wh2, src2, dst2, bm);
        attn2_kernel<<<GN / 4, 256, 0, stream>>>(Wh2, src2, dst2, bm, out);
    }
}

// Round 15
// 52.960 us; speedup vs baseline: 2.0027x; 2.0027x over previous
//
#include <hip/hip_runtime.h>

// GAT: N=4096, F_IN=128, F_HID=64, H=4, F_OUT=64, alpha=0.2
// R15: coalesced adj scan (ballot-packed bitmask, permuted bit mapping).
#define GN 4096
#define F_IN 128
#define F_HID 64
#define NHEADS 4
#define F_OUT 64
#define ALPHA 0.2f
#define NGEMM 512          // GEMM blocks in K1 (8 nodes each), placed FIRST

// workspace layout (bytes)
#define OFF_WH     0           // GN*256*4 = 4 MB   [i][head*64+f]
#define OFF_SRC1   4194304     // GN*4*4             [i][head]
#define OFF_DST1   4259840     // GN*4*4
#define OFF_WH2    4325376     // GN*64*4 = 1 MB
#define OFF_SRC2   5373952     // GN*4
#define OFF_DST2   5390336     // GN*4
#define OFF_BM     5406720     // GN*64 ulong = 2 MB (permuted bit layout, see map)

// Bit mapping: word W = k*16 + wave*4 + j  (k=load idx, wave, j=float4 comp),
// bit l  <->  column  k*1024 + wave*256 + l*4 + j.
// Neighbor emission order is permuted vs ascending — set semantics only
// (softmax/accumulate order changes rounding, not results beyond ~1e-7).

// ===== K1: [GEMM blocks 0..511] + [COALESCED scan blocks 512..4607, 1 row each] =====
__global__ __launch_bounds__(256) void prep_kernel(
        const float* __restrict__ adj, const float* __restrict__ x,
        const float* __restrict__ linW, const float* __restrict__ linb,
        const float* __restrict__ Wheads, const float* __restrict__ aheads,
        float* __restrict__ Wh, float* __restrict__ src1, float* __restrict__ dst1,
        unsigned long long* __restrict__ bm) {
    __shared__ struct { float xs[8][128]; float hs[8][128]; } sm;
    const int tid = threadIdx.x;

    if (blockIdx.x >= NGEMM) {
        const int row  = blockIdx.x - NGEMM;
        const int wave = tid >> 6, lane = tid & 63;
        const float4* rowf4 = (const float4*)(adj + (size_t)row * GN);
        unsigned long long* bmr = bm + (size_t)row * 64;
        #pragma unroll
        for (int k = 0; k < 4; ++k) {
            float4 v = rowf4[k * 256 + tid];          // lane-contiguous: coalesced
            unsigned long long B0 = __ballot(v.x > 0.0f);
            unsigned long long B1 = __ballot(v.y > 0.0f);
            unsigned long long B2 = __ballot(v.z > 0.0f);
            unsigned long long B3 = __ballot(v.w > 0.0f);
            if      (lane == 0) bmr[k * 16 + wave * 4 + 0] = B0;
            else if (lane == 1) bmr[k * 16 + wave * 4 + 1] = B1;
            else if (lane == 2) bmr[k * 16 + wave * 4 + 2] = B2;
            else if (lane == 3) bmr[k * 16 + wave * 4 + 3] = B3;
        }
        return;
    }

    // ---- fused GEMMs: h = x@linW+b ; Wh = h@W_heads ; src1/dst1 (8 nodes) ----
    const int i0 = blockIdx.x * 8;
    #pragma unroll
    for (int t = 0; t < 4; ++t) {
        int e = t * 256 + tid;
        sm.xs[e >> 7][e & 127] = x[(size_t)i0 * 128 + e];
    }
    __syncthreads();
    {
        const int k = tid & 127;
        const int n0 = tid >> 7;
        float bk = linb[k];
        float a0 = bk, a1 = bk, a2 = bk, a3 = bk;
        for (int j = 0; j < 128; ++j) {
            float w = linW[j * 128 + k];
            a0 += sm.xs[n0][j] * w;
            a1 += sm.xs[n0 + 2][j] * w;
            a2 += sm.xs[n0 + 4][j] * w;
            a3 += sm.xs[n0 + 6][j] * w;
        }
        sm.hs[n0][k] = a0; sm.hs[n0 + 2][k] = a1;
        sm.hs[n0 + 4][k] = a2; sm.hs[n0 + 6][k] = a3;
    }
    __syncthreads();
    {
        const int hd = tid >> 6, f = tid & 63;
        float acc[8] = {0, 0, 0, 0, 0, 0, 0, 0};
        const float* Wp = Wheads + (size_t)hd * F_IN * F_HID + f;
        for (int j = 0; j < 128; ++j) {
            float w = Wp[j * 64];
            #pragma unroll
            for (int n = 0; n < 8; ++n) acc[n] += sm.hs[n][j] * w;
        }
        const float as = aheads[hd * 128 + f];
        const float ad = aheads[hd * 128 + 64 + f];
        #pragma unroll
        for (int n = 0; n < 8; ++n) {
            Wh[(size_t)(i0 + n) * 256 + hd * 64 + f] = acc[n];
            float sv = acc[n] * as, dv = acc[n] * ad;
            #pragma unroll
            for (int o = 32; o > 0; o >>= 1) {
                sv += __shfl_xor(sv, o, 64);
                dv += __shfl_xor(dv, o, 64);
            }
            if (f == 0) { src1[(i0 + n) * 4 + hd] = sv; dst1[(i0 + n) * 4 + hd] = dv; }
        }
    }
}

// --- per-wave: build row's neighbor list from the PERMUTED bitmask into LDS ---
__device__ __forceinline__ int build_row_nbrs(const unsigned long long* __restrict__ bm,
                                              int row, int lane, int* sidx) {
    unsigned long long bits = bm[(size_t)row * 64 + lane];
    int c = __popcll(bits);
    int inc = c;
    #pragma unroll
    for (int o = 1; o < 64; o <<= 1) {
        int n = __shfl_up(inc, o, 64);
        if (lane >= o) inc += n;
    }
    int p = inc - c;
    const int deg = __shfl(inc, 63, 64);
    // invert the scan's mapping: W=lane -> k=W>>4, w=(W>>2)&3, j=W&3
    const int col0 = ((lane >> 4) << 10) + (((lane >> 2) & 3) << 8) + (lane & 3);
    while (bits) {
        int b = __ffsll((long long)bits) - 1;
        if (p < 136) sidx[p] = col0 + (b << 2);
        ++p;
        bits &= bits - 1;
    }
    const int deg4 = (deg + 3) & ~3;
    if (lane < deg4 - deg) sidx[deg + lane] = 0;   // pads: weight will be exactly 0
    return deg;
}

// ===== K2: layer-1 attention (all heads, wave/row) + Wend projection, hcat in LDS =====
__global__ __launch_bounds__(256) void attn_mid_kernel(
        const float* __restrict__ Wh, const float* __restrict__ src1,
        const float* __restrict__ dst1, const float* __restrict__ Wend,
        const float* __restrict__ aend, float* __restrict__ Wh2,
        float* __restrict__ src2, float* __restrict__ dst2,
        const unsigned long long* __restrict__ bm) {
    __shared__ float ps[4][528];
    __shared__ float hcat[4][256];
    __shared__ int   sidx[4][136];
    const int wave = threadIdx.x >> 6;
    const int lane = threadIdx.x & 63;
    const int row  = blockIdx.x * 4 + wave;

    const int deg = build_row_nbrs(bm, row, lane, sidx[wave]);
    const int* nb = sidx[wave];
    const int nchunk = (deg + 63) >> 6;

    const float4 s4 = ((const float4*)src1)[row];
    float4 ev[2];
    float4 m4 = make_float4(-1e30f, -1e30f, -1e30f, -1e30f);
    for (int c = 0; c < nchunk; ++c) {
        int t = c * 64 + lane;
        float4 e = make_float4(-1e30f, -1e30f, -1e30f, -1e30f);
        if (t < deg) {
            int j = nb[t];
            float4 d = ((const float4*)dst1)[j];
            e.x = s4.x + d.x; e.x = (e.x > 0.0f) ? e.x : ALPHA * e.x;
            e.y = s4.y + d.y; e.y = (e.y > 0.0f) ? e.y : ALPHA * e.y;
            e.z = s4.z + d.z; e.z = (e.z > 0.0f) ? e.z : ALPHA * e.z;
            e.w = s4.w + d.w; e.w = (e.w > 0.0f) ? e.w : ALPHA * e.w;
        }
        ev[c] = e;
        m4.x = fmaxf(m4.x, e.x); m4.y = fmaxf(m4.y, e.y);
        m4.z = fmaxf(m4.z, e.z); m4.w = fmaxf(m4.w, e.w);
    }
    #pragma unroll
    for (int o = 32; o > 0; o >>= 1) {
        m4.x = fmaxf(m4.x, __shfl_xor(m4.x, o, 64));
        m4.y = fmaxf(m4.y, __shfl_xor(m4.y, o, 64));
        m4.z = fmaxf(m4.z, __shfl_xor(m4.z, o, 64));
        m4.w = fmaxf(m4.w, __shfl_xor(m4.w, o, 64));
    }
    float4 l4 = make_float4(0.f, 0.f, 0.f, 0.f);
    for (int c = 0; c < nchunk; ++c) {
        ev[c].x = expf(ev[c].x - m4.x); l4.x += ev[c].x;
        ev[c].y = expf(ev[c].y - m4.y); l4.y += ev[c].y;
        ev[c].z = expf(ev[c].z - m4.z); l4.z += ev[c].z;
        ev[c].w = expf(ev[c].w - m4.w); l4.w += ev[c].w;
    }
    #pragma unroll
    for (int o = 32; o > 0; o >>= 1) {
        l4.x += __shfl_xor(l4.x, o, 64);
        l4.y += __shfl_xor(l4.y, o, 64);
        l4.z += __shfl_xor(l4.z, o, 64);
        l4.w += __shfl_xor(l4.w, o, 64);
    }
    const float4 inv = make_float4(1.f / l4.x, 1.f / l4.y, 1.f / l4.z, 1.f / l4.w);
    for (int c = 0; c < nchunk; ++c) {
        int t = c * 64 + lane;
        float4 p = make_float4(ev[c].x * inv.x, ev[c].y * inv.y,
                               ev[c].z * inv.z, ev[c].w * inv.w);
        ((float4*)&ps[wave][0])[t] = p;
    }

    const int hl = lane >> 4;
    const float4* Wh4 = (const float4*)Wh;
    float4 acc = make_float4(0.f, 0.f, 0.f, 0.f);
    const int deg4 = (deg + 3) & ~3;
    for (int t = 0; t < deg4; t += 4) {
        int4 jj = *(const int4*)(nb + t);
        float4 w0 = Wh4[(size_t)jj.x * 64 + lane];
        float4 w1 = Wh4[(size_t)jj.y * 64 + lane];
        float4 w2 = Wh4[(size_t)jj.z * 64 + lane];
        float4 w3 = Wh4[(size_t)jj.w * 64 + lane];
        const float* pp = &ps[wave][t * 4 + hl];
        float p0 = pp[0], p1 = pp[4], p2 = pp[8], p3 = pp[12];
        acc.x += p0 * w0.x + p1 * w1.x + p2 * w2.x + p3 * w3.x;
        acc.y += p0 * w0.y + p1 * w1.y + p2 * w2.y + p3 * w3.y;
        acc.z += p0 * w0.z + p1 * w1.z + p2 * w2.z + p3 * w3.z;
        acc.w += p0 * w0.w + p1 * w1.w + p2 * w2.w + p3 * w3.w;
    }
    acc.x = (acc.x > 0.0f) ? acc.x : expm1f(acc.x);
    acc.y = (acc.y > 0.0f) ? acc.y : expm1f(acc.y);
    acc.z = (acc.z > 0.0f) ? acc.z : expm1f(acc.z);
    acc.w = (acc.w > 0.0f) ? acc.w : expm1f(acc.w);
    ((float4*)hcat[wave])[lane] = acc;

    float a0 = 0.f, a1 = 0.f, a2 = 0.f, a3 = 0.f;
    const float* Wp = Wend + lane;
    #pragma unroll 4
    for (int j = 0; j < 256; j += 4) {
        a0 += hcat[wave][j    ] * Wp[(j    ) * 64];
        a1 += hcat[wave][j + 1] * Wp[(j + 1) * 64];
        a2 += hcat[wave][j + 2] * Wp[(j + 2) * 64];
        a3 += hcat[wave][j + 3] * Wp[(j + 3) * 64];
    }
    float aa = (a0 + a1) + (a2 + a3);
    Wh2[(size_t)row * 64 + lane] = aa;
    float s0 = aa * aend[lane], d0 = aa * aend[64 + lane];
    #pragma unroll
    for (int o = 32; o > 0; o >>= 1) {
        s0 += __shfl_xor(s0, o, 64); d0 += __shfl_xor(d0, o, 64);
    }
    if (lane == 0) { src2[row] = s0; dst2[row] = d0; }
}

// ===== K3: layer-2 attention + elu + final row softmax; wave per row =====
__global__ __launch_bounds__(256) void attn2_kernel(
        const float* __restrict__ Wh2, const float* __restrict__ src,
        const float* __restrict__ dst, const unsigned long long* __restrict__ bm,
        float* __restrict__ out) {
    __shared__ int sidx[4][136];
    const int wave = threadIdx.x >> 6;
    const int lane = threadIdx.x & 63;
    const int row  = blockIdx.x * 4 + wave;

    const int deg = build_row_nbrs(bm, row, lane, sidx[wave]);
    const int* nb = sidx[wave];
    const float s_i = src[row];

    float e[2];
    #pragma unroll
    for (int c = 0; c < 2; ++c) {
        int t = c * 64 + lane;
        float ev = -1e30f;
        if (t < deg) {
            int j = nb[t];
            ev = s_i + dst[j];
            ev = (ev > 0.0f) ? ev : ALPHA * ev;
        }
        e[c] = ev;
    }
    float m = fmaxf(e[0], e[1]);
    #pragma unroll
    for (int o = 32; o > 0; o >>= 1) m = fmaxf(m, __shfl_xor(m, o, 64));
    float l = 0.0f;
    #pragma unroll
    for (int c = 0; c < 2; ++c) { e[c] = expf(e[c] - m); l += e[c]; }
    #pragma unroll
    for (int o = 32; o > 0; o >>= 1) l += __shfl_xor(l, o, 64);

    float accA = 0.0f, accB = 0.0f;
    const float* W2 = Wh2 + lane;
    #pragma unroll
    for (int c = 0; c < 2; ++c) {
        int base = c * 64;
        if (base >= deg) break;
        int nmax = deg - base; if (nmax > 64) nmax = 64;
        int n4 = (nmax + 3) & ~3;
        for (int t = 0; t < n4; t += 4) {
            int4 jj = *(const int4*)(nb + base + t);
            float w0 = W2[(size_t)jj.x * 64];
            float w1 = W2[(size_t)jj.y * 64];
            float w2 = W2[(size_t)jj.z * 64];
            float w3 = W2[(size_t)jj.w * 64];
            float p0 = __shfl(e[c], t, 64),     p1 = __shfl(e[c], t + 1, 64);
            float p2 = __shfl(e[c], t + 2, 64), p3 = __shfl(e[c], t + 3, 64);
            accA += p0 * w0 + p2 * w2;
            accB += p1 * w1 + p3 * w3;
        }
    }
    float v = (accA + accB) / l;
    v = (v > 0.0f) ? v : expm1f(v);    // elu

    float mm = v;
    #pragma unroll
    for (int o = 32; o > 0; o >>= 1) mm = fmaxf(mm, __shfl_xor(mm, o, 64));
    float ee = expf(v - mm);
    float ss = ee;
    #pragma unroll
    for (int o = 32; o > 0; o >>= 1) ss += __shfl_xor(ss, o, 64);
    out[(size_t)row * F_OUT + lane] = ee / ss;
}

extern "C" void kernel_launch(void* const* d_in, const int* in_sizes, int n_in,
                              void* d_out, int out_size, void* d_ws, size_t ws_size,
                              hipStream_t stream) {
    const float* x      = (const float*)d_in[0];
    const float* adj    = (const float*)d_in[1];
    const float* lin_W  = (const float*)d_in[2];
    const float* lin_b  = (const float*)d_in[3];
    const float* Wheads = (const float*)d_in[4];
    const float* aheads = (const float*)d_in[5];
    const float* Wend   = (const float*)d_in[6];
    const float* aend   = (const float*)d_in[7];
    float* out = (float*)d_out;

    char* ws = (char*)d_ws;
    float* Wh   = (float*)(ws + OFF_WH);
    float* src1 = (float*)(ws + OFF_SRC1);
    float* dst1 = (float*)(ws + OFF_DST1);
    float* Wh2  = (float*)(ws + OFF_WH2);
    float* src2 = (float*)(ws + OFF_SRC2);
    float* dst2 = (float*)(ws + OFF_DST2);
    unsigned long long* bm = (unsigned long long*)(ws + OFF_BM);

    prep_kernel<<<NGEMM + GN, 256, 0, stream>>>(adj, x, lin_W, lin_b, Wheads, aheads,
                                                Wh, src1, dst1, bm);
    attn_mid_kernel<<<GN / 4, 256, 0, stream>>>(Wh, src1, dst1, Wend, aend,
                                                Wh2, src2, dst2, bm);
    attn2_kernel<<<GN / 4, 256, 0, stream>>>(Wh2, src2, dst2, bm, out);
}